// Round 2
// baseline (12768.465 us; speedup 1.0000x reference)
//
#include <hip/hip_runtime.h>
#include <hip/hip_bf16.h>
#include <stdint.h>

typedef __bf16 bf16_t;
typedef __attribute__((ext_vector_type(8))) __bf16 bf16x8_t;
typedef __attribute__((ext_vector_type(4))) __bf16 bf16x4_t;
typedef __attribute__((ext_vector_type(4))) float f32x4_t;

#define NB 64
#define SEQ 512
#define NCLASS 32000
#define EMBD 512
#define HIDD 1024
#define BH (NB * HIDD)  // 65536

__device__ __forceinline__ void split_bf16(float x, bf16_t& h, bf16_t& l) {
  h = (bf16_t)x;
  l = (bf16_t)(x - (float)h);
}

// ---------------- init: W_ih -> bf16 hi/lo, zero flags -----------------------
__global__ __launch_bounds__(256) void k_init(const float* __restrict__ Wih,
                                              bf16_t* __restrict__ Wh,
                                              bf16_t* __restrict__ Wl,
                                              int* __restrict__ flags) {
  int i = blockIdx.x * 256 + threadIdx.x;
  if (i < HIDD * EMBD) {
    bf16_t h, l;
    split_bf16(Wih[i], h, l);
    Wh[i] = h; Wl[i] = l;
  }
  if (i < 64) flags[i] = 0;
}

// ---------------- gather embedding rows -> bf16 hi/lo, (t*64+b, EMBD) --------
__global__ __launch_bounds__(128) void k_embg(const int* __restrict__ X,
                                              const float* __restrict__ emb,
                                              bf16_t* __restrict__ Eh,
                                              bf16_t* __restrict__ El) {
  int row = blockIdx.x;  // row = t*64 + b
  int t = row >> 6, b = row & 63;
  int idx = X[b * SEQ + t];
  const f32x4_t* src = (const f32x4_t*)(emb + (size_t)idx * EMBD);
  f32x4_t v = src[threadIdx.x];
  bf16x4_t oh, ol;
#pragma unroll
  for (int j = 0; j < 4; ++j) {
    bf16_t h, l; split_bf16(v[j], h, l); oh[j] = h; ol[j] = l;
  }
  ((bf16x4_t*)(Eh + (size_t)row * EMBD))[threadIdx.x] = oh;
  ((bf16x4_t*)(El + (size_t)row * EMBD))[threadIdx.x] = ol;
}

// ---------------- pre = embg @ W_ih^T + b_ih + b_hh  (split-bf16, 3-pass) ----
// M=32768, N=1024, K=512.  BM=BN=128, BK=64, 4 waves in 2x2, wave tile 64x64.
__global__ __launch_bounds__(256) void k_pre(const bf16_t* __restrict__ Ah,
                                             const bf16_t* __restrict__ Al,
                                             const bf16_t* __restrict__ Bh,
                                             const bf16_t* __restrict__ Bl,
                                             const float* __restrict__ bih,
                                             const float* __restrict__ bhh,
                                             float* __restrict__ pre) {
  __shared__ bf16_t Ash[128 * 64];
  __shared__ bf16_t Asl[128 * 64];
  __shared__ bf16_t Bsh[128 * 64];
  __shared__ bf16_t Bsl[128 * 64];
  const int m0 = blockIdx.x * 128;
  const int n0 = blockIdx.y * 128;
  const int tid = threadIdx.x;
  const int w = tid >> 6, lane = tid & 63;
  const int lr = lane & 15, lk16 = lane >> 4;
  const int wr = w >> 1, wc = w & 1;
  const int srow = lane >> 3;
  const int scol = (lane & 7) * 8;
  f32x4_t acc[4][4];
#pragma unroll
  for (int i = 0; i < 4; ++i)
#pragma unroll
    for (int j = 0; j < 4; ++j) acc[i][j] = (f32x4_t){0.f, 0.f, 0.f, 0.f};

  for (int kt = 0; kt < 8; ++kt) {
    const int k0 = kt * 64;
#pragma unroll
    for (int i = 0; i < 4; ++i) {
      int c = w * 4 + i;                 // chunk 0..15, wave-uniform
      int row = c * 8 + srow;
      size_t goA = (size_t)(m0 + row) * EMBD + k0 + scol;
      size_t goB = (size_t)(n0 + row) * EMBD + k0 + scol;
      __builtin_amdgcn_global_load_lds((const __attribute__((address_space(1))) void*)(Ah + goA),
                                       (__attribute__((address_space(3))) void*)(Ash + c * 512), 16, 0, 0);
      __builtin_amdgcn_global_load_lds((const __attribute__((address_space(1))) void*)(Al + goA),
                                       (__attribute__((address_space(3))) void*)(Asl + c * 512), 16, 0, 0);
      __builtin_amdgcn_global_load_lds((const __attribute__((address_space(1))) void*)(Bh + goB),
                                       (__attribute__((address_space(3))) void*)(Bsh + c * 512), 16, 0, 0);
      __builtin_amdgcn_global_load_lds((const __attribute__((address_space(1))) void*)(Bl + goB),
                                       (__attribute__((address_space(3))) void*)(Bsl + c * 512), 16, 0, 0);
    }
    __syncthreads();
#pragma unroll
    for (int kk = 0; kk < 2; ++kk) {
      bf16x8_t afh[4], afl[4], bqh[4], bql[4];
#pragma unroll
      for (int mi = 0; mi < 4; ++mi) {
        int off = (wr * 64 + mi * 16 + lr) * 64 + kk * 32 + lk16 * 8;
        afh[mi] = *(const bf16x8_t*)(Ash + off);
        afl[mi] = *(const bf16x8_t*)(Asl + off);
      }
#pragma unroll
      for (int ni = 0; ni < 4; ++ni) {
        int off = (wc * 64 + ni * 16 + lr) * 64 + kk * 32 + lk16 * 8;
        bqh[ni] = *(const bf16x8_t*)(Bsh + off);
        bql[ni] = *(const bf16x8_t*)(Bsl + off);
      }
#pragma unroll
      for (int mi = 0; mi < 4; ++mi)
#pragma unroll
        for (int ni = 0; ni < 4; ++ni) {
          acc[mi][ni] = __builtin_amdgcn_mfma_f32_16x16x32_bf16(afh[mi], bqh[ni], acc[mi][ni], 0, 0, 0);
          acc[mi][ni] = __builtin_amdgcn_mfma_f32_16x16x32_bf16(afh[mi], bql[ni], acc[mi][ni], 0, 0, 0);
          acc[mi][ni] = __builtin_amdgcn_mfma_f32_16x16x32_bf16(afl[mi], bqh[ni], acc[mi][ni], 0, 0, 0);
        }
    }
    __syncthreads();
  }
#pragma unroll
  for (int ni = 0; ni < 4; ++ni) {
    int col = n0 + wc * 64 + ni * 16 + lr;
    float bias = bih[col] + bhh[col];
#pragma unroll
    for (int mi = 0; mi < 4; ++mi) {
      int rowg = m0 + wr * 64 + mi * 16 + lk16 * 4;
      float* p = pre + (size_t)rowg * HIDD + col;
#pragma unroll
      for (int i = 0; i < 4; ++i) p[(size_t)i * HIDD] = acc[mi][ni][i] + bias;
    }
  }
}

// ---------------- persistent RNN: 64 blocks, 16 cols each, split W_hh in VGPRs
// h state stored as bf16 hi/lo pair (slot t holds h_{t+1}; h_0 = 0 implicit).
__global__ __launch_bounds__(256, 1) void k_rnn(const float* __restrict__ Whh,
                                                const float* __restrict__ pre,
                                                bf16_t* __restrict__ Hh,
                                                bf16_t* __restrict__ Hl,
                                                int* __restrict__ flags) {
  const int bid = blockIdx.x;  // 0..63
  const int tid = threadIdx.x;
  const int w = tid >> 6, lane = tid & 63;
  const int lr = lane & 15;
  const int lk = (lane >> 4) * 8;

  // weight-stationary fragments: w[kk][j] = Whh[bid*16+lr][kk*32+lk+j], hi+lo
  bf16x8_t wfh[32], wfl[32];
  {
    const float* wrow = Whh + (size_t)(bid * 16 + lr) * HIDD + lk;
#pragma unroll
    for (int kk = 0; kk < 32; ++kk) {
      bf16x8_t fh, fl;
#pragma unroll
      for (int j = 0; j < 8; ++j) {
        bf16_t h, l; split_bf16(wrow[kk * 32 + j], h, l);
        fh[j] = h; fl[j] = l;
      }
      wfh[kk] = fh; wfl[kk] = fl;
    }
  }

  const int colg = bid * 16 + lr;
  const int rowb = w * 16 + (lane >> 4) * 4;
  const size_t aoff = (size_t)(w * 16 + lr) * HIDD + lk;

  for (int t = 0; t < SEQ; ++t) {
    float xs0 = 0.f, xs1 = 0.f, xs2 = 0.f, xs3 = 0.f;
    if (t > 0) {
      const bf16_t* arh = Hh + (size_t)(t - 1) * BH + aoff;
      const bf16_t* arl = Hl + (size_t)(t - 1) * BH + aoff;
      f32x4_t a0a = {0.f,0.f,0.f,0.f}, a0b = {0.f,0.f,0.f,0.f};
      f32x4_t a1a = {0.f,0.f,0.f,0.f}, a1b = {0.f,0.f,0.f,0.f};
      f32x4_t a2a = {0.f,0.f,0.f,0.f}, a2b = {0.f,0.f,0.f,0.f};
#pragma unroll
      for (int kk = 0; kk < 32; kk += 2) {
        bf16x8_t h0 = *(const bf16x8_t*)(arh + kk * 32);
        bf16x8_t l0 = *(const bf16x8_t*)(arl + kk * 32);
        bf16x8_t h1 = *(const bf16x8_t*)(arh + (kk + 1) * 32);
        bf16x8_t l1 = *(const bf16x8_t*)(arl + (kk + 1) * 32);
        a0a = __builtin_amdgcn_mfma_f32_16x16x32_bf16(h0, wfh[kk], a0a, 0, 0, 0);
        a1a = __builtin_amdgcn_mfma_f32_16x16x32_bf16(h0, wfl[kk], a1a, 0, 0, 0);
        a2a = __builtin_amdgcn_mfma_f32_16x16x32_bf16(l0, wfh[kk], a2a, 0, 0, 0);
        a0b = __builtin_amdgcn_mfma_f32_16x16x32_bf16(h1, wfh[kk + 1], a0b, 0, 0, 0);
        a1b = __builtin_amdgcn_mfma_f32_16x16x32_bf16(h1, wfl[kk + 1], a1b, 0, 0, 0);
        a2b = __builtin_amdgcn_mfma_f32_16x16x32_bf16(l1, wfh[kk + 1], a2b, 0, 0, 0);
      }
      xs0 = (a0a[0] + a0b[0]) + (a1a[0] + a1b[0]) + (a2a[0] + a2b[0]);
      xs1 = (a0a[1] + a0b[1]) + (a1a[1] + a1b[1]) + (a2a[1] + a2b[1]);
      xs2 = (a0a[2] + a0b[2]) + (a1a[2] + a1b[2]) + (a2a[2] + a2b[2]);
      xs3 = (a0a[3] + a0b[3]) + (a1a[3] + a1b[3]) + (a2a[3] + a2b[3]);
    }
    const float* prow = pre + (size_t)t * BH + (size_t)rowb * HIDD + colg;
    bf16_t* nh = Hh + (size_t)t * BH + (size_t)rowb * HIDD + colg;
    bf16_t* nl = Hl + (size_t)t * BH + (size_t)rowb * HIDD + colg;
    float xv[4] = {xs0, xs1, xs2, xs3};
#pragma unroll
    for (int i = 0; i < 4; ++i) {
      float x = xv[i] + prow[(size_t)i * HIDD];
      float e = __expf(2.0f * x);
      float h = 1.0f - 2.0f / (e + 1.0f);
      bf16_t hh, hl; split_bf16(h, hh, hl);
      nh[(size_t)i * HIDD] = hh;
      nl[(size_t)i * HIDD] = hl;
    }
    __threadfence();          // agent release: make h stores device-visible
    __syncthreads();
    if (tid == 0) __hip_atomic_store(flags + bid, t + 1, __ATOMIC_RELEASE, __HIP_MEMORY_SCOPE_AGENT);
    if (w == 0) {
      int target = t + 1;
      while (__hip_atomic_load(flags + lane, __ATOMIC_ACQUIRE, __HIP_MEMORY_SCOPE_AGENT) < target) { }
    }
    __syncthreads();
  }
}

// ---------------- attention + feat assembly: one block per batch row ---------
// slots 0..510 = prev (h_1..h_511), slot 511 = last (h_512)
__global__ __launch_bounds__(256) void k_attn(const bf16_t* __restrict__ Hh,
                                              const bf16_t* __restrict__ Hl,
                                              bf16_t* __restrict__ feat) {
  __shared__ float sc[512];
  __shared__ float lastf[HIDD];
  __shared__ float red[256];
  const int b = blockIdx.x, tid = threadIdx.x;
  const size_t lastoff = (size_t)511 * BH + (size_t)b * HIDD;
  for (int i = tid; i < HIDD; i += 256)
    lastf[i] = (float)Hh[lastoff + i] + (float)Hl[lastoff + i];
  __syncthreads();
  for (int s = tid; s < 511; s += 256) {
    const size_t hoff = (size_t)s * BH + (size_t)b * HIDD;
    float acc = 0.f;
    for (int k = 0; k < HIDD; k += 8) {
      bf16x8_t vh = *(const bf16x8_t*)(Hh + hoff + k);
      bf16x8_t vl = *(const bf16x8_t*)(Hl + hoff + k);
#pragma unroll
      for (int j = 0; j < 8; ++j)
        acc += ((float)vh[j] + (float)vl[j]) * lastf[k + j];
    }
    sc[s] = acc;
  }
  if (tid == 0) sc[511] = -3.0e38f;
  __syncthreads();
  float m = fmaxf(sc[tid], sc[tid + 256]);
  red[tid] = m; __syncthreads();
  for (int off = 128; off > 0; off >>= 1) {
    if (tid < off) red[tid] = fmaxf(red[tid], red[tid + off]);
    __syncthreads();
  }
  float mall = red[0];
  __syncthreads();
  float e0 = __expf(sc[tid] - mall);
  float e1 = (tid + 256 < 511) ? __expf(sc[tid + 256] - mall) : 0.f;
  red[tid] = e0 + e1; __syncthreads();
  for (int off = 128; off > 0; off >>= 1) {
    if (tid < off) red[tid] += red[tid + off];
    __syncthreads();
  }
  float rsum = 1.0f / red[0];
  __syncthreads();
  sc[tid] = e0 * rsum;
  if (tid + 256 < 511) sc[tid + 256] = e1 * rsum;
  __syncthreads();
  float a0 = 0.f, a1 = 0.f, a2 = 0.f, a3 = 0.f;
  const size_t hb = (size_t)b * HIDD + 4 * tid;
  for (int s = 0; s < 511; ++s) {
    float wgt = sc[s];
    bf16x4_t vh = *(const bf16x4_t*)(Hh + hb + (size_t)s * BH);
    bf16x4_t vl = *(const bf16x4_t*)(Hl + hb + (size_t)s * BH);
    a0 += wgt * ((float)vh[0] + (float)vl[0]);
    a1 += wgt * ((float)vh[1] + (float)vl[1]);
    a2 += wgt * ((float)vh[2] + (float)vl[2]);
    a3 += wgt * ((float)vh[3] + (float)vl[3]);
  }
  bf16x4_t o;
  o[0] = (bf16_t)a0; o[1] = (bf16_t)a1; o[2] = (bf16_t)a2; o[3] = (bf16_t)a3;
  *(bf16x4_t*)(feat + (size_t)b * 2048 + 4 * tid) = o;
  for (int i = tid; i < HIDD; i += 256)
    feat[(size_t)b * 2048 + 1024 + i] = (bf16_t)lastf[i];
}

// ---------------- out = feat @ W_out^T + b_out : M=64,N=32000,K=2048 ---------
__global__ __launch_bounds__(256) void k_out(const bf16_t* __restrict__ feat,
                                             const float* __restrict__ Wout,
                                             const float* __restrict__ bout,
                                             float* __restrict__ out) {
  __shared__ bf16_t As[64 * 64];
  __shared__ bf16_t Bs[128 * 64];
  const int n0 = blockIdx.x * 128;
  const int tid = threadIdx.x;
  const int w = tid >> 6, lane = tid & 63;
  const int lr = lane & 15, lk16 = lane >> 4;
  const int srow = lane >> 3, scol = (lane & 7) * 8;
  f32x4_t acc[4][2];
#pragma unroll
  for (int i = 0; i < 4; ++i)
#pragma unroll
    for (int j = 0; j < 2; ++j) acc[i][j] = (f32x4_t){0.f, 0.f, 0.f, 0.f};

  for (int kt = 0; kt < 32; ++kt) {
    const int k0 = kt * 64;
#pragma unroll
    for (int i = 0; i < 2; ++i) {
      int c = w * 2 + i;  // 0..7, wave-uniform
      const bf16_t* ga = feat + (size_t)(c * 8 + srow) * 2048 + k0 + scol;
      __builtin_amdgcn_global_load_lds((const __attribute__((address_space(1))) void*)ga,
                                       (__attribute__((address_space(3))) void*)(As + c * 512), 16, 0, 0);
    }
    {
      int row = tid >> 1;
      int cbase = (tid & 1) * 32;
      const float* gb = Wout + (size_t)(n0 + row) * 2048 + k0 + cbase;
      bf16_t* db = Bs + row * 64 + cbase;
#pragma unroll
      for (int j = 0; j < 8; ++j) {
        f32x4_t v = *(const f32x4_t*)(gb + j * 4);
        bf16x4_t o;
        o[0] = (bf16_t)v.x; o[1] = (bf16_t)v.y; o[2] = (bf16_t)v.z; o[3] = (bf16_t)v.w;
        *(bf16x4_t*)(db + j * 4) = o;
      }
    }
    __syncthreads();
#pragma unroll
    for (int kk = 0; kk < 2; ++kk) {
      bf16x8_t af[4], bq[2];
#pragma unroll
      for (int mi = 0; mi < 4; ++mi)
        af[mi] = *(const bf16x8_t*)(As + (mi * 16 + lr) * 64 + kk * 32 + lk16 * 8);
#pragma unroll
      for (int ni = 0; ni < 2; ++ni)
        bq[ni] = *(const bf16x8_t*)(Bs + (w * 32 + ni * 16 + lr) * 64 + kk * 32 + lk16 * 8);
#pragma unroll
      for (int mi = 0; mi < 4; ++mi)
#pragma unroll
        for (int ni = 0; ni < 2; ++ni)
          acc[mi][ni] = __builtin_amdgcn_mfma_f32_16x16x32_bf16(af[mi], bq[ni], acc[mi][ni], 0, 0, 0);
    }
    __syncthreads();
  }
#pragma unroll
  for (int ni = 0; ni < 2; ++ni) {
    int col = n0 + w * 32 + ni * 16 + lr;
    float bo = bout[col];
#pragma unroll
    for (int mi = 0; mi < 4; ++mi) {
      int row = mi * 16 + lk16 * 4;
      float* p = out + (size_t)row * NCLASS + col;
#pragma unroll
      for (int i = 0; i < 4; ++i) p[(size_t)i * NCLASS] = acc[mi][ni][i] + bo;
    }
  }
}

extern "C" void kernel_launch(void* const* d_in, const int* in_sizes, int n_in,
                              void* d_out, int out_size, void* d_ws, size_t ws_size,
                              hipStream_t stream) {
  const int*   X    = (const int*)d_in[0];
  const float* emb  = (const float*)d_in[1];
  const float* Wih  = (const float*)d_in[2];
  const float* Whh  = (const float*)d_in[3];
  const float* bih  = (const float*)d_in[4];
  const float* bhh  = (const float*)d_in[5];
  const float* Wout = (const float*)d_in[6];
  const float* bout = (const float*)d_in[7];
  float* out = (float*)d_out;

  char* ws = (char*)d_ws;
  // region A: pre (f32), alive k_pre -> k_rnn
  float*  pre    = (float*)(ws);                      // 134,217,728 B
  // region B (union, temporally disjoint users):
  //   phase1 (k_embg/k_pre): embg hi/lo + Wih hi/lo
  bf16_t* Eh     = (bf16_t*)(ws + 134217728);         // 33,554,432 B
  bf16_t* El     = (bf16_t*)(ws + 167772160);         // 33,554,432 B
  bf16_t* Wihh   = (bf16_t*)(ws + 201326592);         //  1,048,576 B
  bf16_t* Wihl   = (bf16_t*)(ws + 202375168);         //  1,048,576 B
  //   phase2 (k_rnn/k_attn): h state hi/lo, 512 slots each
  bf16_t* Hh     = (bf16_t*)(ws + 134217728);         // 67,108,864 B
  bf16_t* Hl     = (bf16_t*)(ws + 201326592);         // 67,108,864 B
  // region C: small
  bf16_t* feat   = (bf16_t*)(ws + 268435456);         //    262,144 B
  int*    flags  = (int*)(ws + 268697600);            //        256 B

  k_init<<<2048, 256, 0, stream>>>(Wih, Wihh, Wihl, flags);
  k_embg<<<32768, 128, 0, stream>>>(X, emb, Eh, El);
  k_pre<<<dim3(256, 8), 256, 0, stream>>>(Eh, El, Wihh, Wihl, bih, bhh, pre);
  k_rnn<<<64, 256, 0, stream>>>(Whh, pre, Hh, Hl, flags);
  k_attn<<<64, 256, 0, stream>>>(Hh, Hl, feat);
  k_out<<<250, 256, 0, stream>>>(feat, Wout, bout, out);
}

// Round 3
// 9284.677 us; speedup vs baseline: 1.3752x; 1.3752x over previous
//
#include <hip/hip_runtime.h>
#include <hip/hip_bf16.h>
#include <stdint.h>

typedef __bf16 bf16_t;
typedef __attribute__((ext_vector_type(8))) __bf16 bf16x8_t;
typedef __attribute__((ext_vector_type(4))) __bf16 bf16x4_t;
typedef __attribute__((ext_vector_type(4))) float f32x4_t;

#define NB 64
#define SEQ 512
#define NCLASS 32000
#define EMBD 512
#define HIDD 1024
#define BH (NB * HIDD)  // 65536

__device__ __forceinline__ void split_bf16(float x, bf16_t& h, bf16_t& l) {
  h = (bf16_t)x;
  l = (bf16_t)(x - (float)h);
}

// --- LIC-coherent (cache-bypassing) access helpers: relaxed SYSTEM scope ---
// Loads/stores compile to sc0+sc1 flagged ops: no L1/L2 allocation, served at
// the memory-side coherency point (Infinity Cache). NO buffer_inv / wbl2.
__device__ __forceinline__ bf16x8_t ld_sys_b16x8(const bf16_t* p) {
  union { unsigned long long u[2]; bf16x8_t v; } c;
  c.u[0] = __hip_atomic_load((const unsigned long long*)p, __ATOMIC_RELAXED,
                             __HIP_MEMORY_SCOPE_SYSTEM);
  c.u[1] = __hip_atomic_load((const unsigned long long*)(p + 4), __ATOMIC_RELAXED,
                             __HIP_MEMORY_SCOPE_SYSTEM);
  return c.v;
}
__device__ __forceinline__ void st_sys_b16(bf16_t* p, bf16_t v) {
  union { bf16_t b; unsigned short u; } c; c.b = v;
  __hip_atomic_store((unsigned short*)p, c.u, __ATOMIC_RELAXED,
                     __HIP_MEMORY_SCOPE_SYSTEM);
}

// ---------------- init: W_ih -> bf16 hi/lo, zero flags -----------------------
__global__ __launch_bounds__(256) void k_init(const float* __restrict__ Wih,
                                              bf16_t* __restrict__ Wh,
                                              bf16_t* __restrict__ Wl,
                                              int* __restrict__ flags) {
  int i = blockIdx.x * 256 + threadIdx.x;
  if (i < HIDD * EMBD) {
    bf16_t h, l;
    split_bf16(Wih[i], h, l);
    Wh[i] = h; Wl[i] = l;
  }
  if (i < 64) flags[i] = 0;
}

// ---------------- gather embedding rows -> bf16 hi/lo, (t*64+b, EMBD) --------
__global__ __launch_bounds__(128) void k_embg(const int* __restrict__ X,
                                              const float* __restrict__ emb,
                                              bf16_t* __restrict__ Eh,
                                              bf16_t* __restrict__ El) {
  int row = blockIdx.x;  // row = t*64 + b
  int t = row >> 6, b = row & 63;
  int idx = X[b * SEQ + t];
  const f32x4_t* src = (const f32x4_t*)(emb + (size_t)idx * EMBD);
  f32x4_t v = src[threadIdx.x];
  bf16x4_t oh, ol;
#pragma unroll
  for (int j = 0; j < 4; ++j) {
    bf16_t h, l; split_bf16(v[j], h, l); oh[j] = h; ol[j] = l;
  }
  ((bf16x4_t*)(Eh + (size_t)row * EMBD))[threadIdx.x] = oh;
  ((bf16x4_t*)(El + (size_t)row * EMBD))[threadIdx.x] = ol;
}

// ---------------- pre = embg @ W_ih^T + b_ih + b_hh  (split-bf16, 3-pass) ----
__global__ __launch_bounds__(256) void k_pre(const bf16_t* __restrict__ Ah,
                                             const bf16_t* __restrict__ Al,
                                             const bf16_t* __restrict__ Bh,
                                             const bf16_t* __restrict__ Bl,
                                             const float* __restrict__ bih,
                                             const float* __restrict__ bhh,
                                             float* __restrict__ pre) {
  __shared__ bf16_t Ash[128 * 64];
  __shared__ bf16_t Asl[128 * 64];
  __shared__ bf16_t Bsh[128 * 64];
  __shared__ bf16_t Bsl[128 * 64];
  const int m0 = blockIdx.x * 128;
  const int n0 = blockIdx.y * 128;
  const int tid = threadIdx.x;
  const int w = tid >> 6, lane = tid & 63;
  const int lr = lane & 15, lk16 = lane >> 4;
  const int wr = w >> 1, wc = w & 1;
  const int srow = lane >> 3;
  const int scol = (lane & 7) * 8;
  f32x4_t acc[4][4];
#pragma unroll
  for (int i = 0; i < 4; ++i)
#pragma unroll
    for (int j = 0; j < 4; ++j) acc[i][j] = (f32x4_t){0.f, 0.f, 0.f, 0.f};

  for (int kt = 0; kt < 8; ++kt) {
    const int k0 = kt * 64;
#pragma unroll
    for (int i = 0; i < 4; ++i) {
      int c = w * 4 + i;                 // chunk 0..15, wave-uniform
      int row = c * 8 + srow;
      size_t goA = (size_t)(m0 + row) * EMBD + k0 + scol;
      size_t goB = (size_t)(n0 + row) * EMBD + k0 + scol;
      __builtin_amdgcn_global_load_lds((const __attribute__((address_space(1))) void*)(Ah + goA),
                                       (__attribute__((address_space(3))) void*)(Ash + c * 512), 16, 0, 0);
      __builtin_amdgcn_global_load_lds((const __attribute__((address_space(1))) void*)(Al + goA),
                                       (__attribute__((address_space(3))) void*)(Asl + c * 512), 16, 0, 0);
      __builtin_amdgcn_global_load_lds((const __attribute__((address_space(1))) void*)(Bh + goB),
                                       (__attribute__((address_space(3))) void*)(Bsh + c * 512), 16, 0, 0);
      __builtin_amdgcn_global_load_lds((const __attribute__((address_space(1))) void*)(Bl + goB),
                                       (__attribute__((address_space(3))) void*)(Bsl + c * 512), 16, 0, 0);
    }
    __syncthreads();
#pragma unroll
    for (int kk = 0; kk < 2; ++kk) {
      bf16x8_t afh[4], afl[4], bqh[4], bql[4];
#pragma unroll
      for (int mi = 0; mi < 4; ++mi) {
        int off = (wr * 64 + mi * 16 + lr) * 64 + kk * 32 + lk16 * 8;
        afh[mi] = *(const bf16x8_t*)(Ash + off);
        afl[mi] = *(const bf16x8_t*)(Asl + off);
      }
#pragma unroll
      for (int ni = 0; ni < 4; ++ni) {
        int off = (wc * 64 + ni * 16 + lr) * 64 + kk * 32 + lk16 * 8;
        bqh[ni] = *(const bf16x8_t*)(Bsh + off);
        bql[ni] = *(const bf16x8_t*)(Bsl + off);
      }
#pragma unroll
      for (int mi = 0; mi < 4; ++mi)
#pragma unroll
        for (int ni = 0; ni < 4; ++ni) {
          acc[mi][ni] = __builtin_amdgcn_mfma_f32_16x16x32_bf16(afh[mi], bqh[ni], acc[mi][ni], 0, 0, 0);
          acc[mi][ni] = __builtin_amdgcn_mfma_f32_16x16x32_bf16(afh[mi], bql[ni], acc[mi][ni], 0, 0, 0);
          acc[mi][ni] = __builtin_amdgcn_mfma_f32_16x16x32_bf16(afl[mi], bqh[ni], acc[mi][ni], 0, 0, 0);
        }
    }
    __syncthreads();
  }
#pragma unroll
  for (int ni = 0; ni < 4; ++ni) {
    int col = n0 + wc * 64 + ni * 16 + lr;
    float bias = bih[col] + bhh[col];
#pragma unroll
    for (int mi = 0; mi < 4; ++mi) {
      int rowg = m0 + wr * 64 + mi * 16 + lk16 * 4;
      float* p = pre + (size_t)rowg * HIDD + col;
#pragma unroll
      for (int i = 0; i < 4; ++i) p[(size_t)i * HIDD] = acc[mi][ni][i] + bias;
    }
  }
}

// ---------------- persistent RNN: 64 blocks, 16 cols each, split W_hh in VGPRs
// h exchange via LIC-coherent (sc0 sc1) loads/stores: NO cache-maintenance ops.
// Sync: stores -> __syncthreads (drains vmcnt => stores at coherency point) ->
// relaxed flag store -> wave0 relaxed-polls 64 flags -> __syncthreads.
__global__ __launch_bounds__(256, 1) void k_rnn(const float* __restrict__ Whh,
                                                const float* __restrict__ pre,
                                                bf16_t* __restrict__ Hh,
                                                bf16_t* __restrict__ Hl,
                                                int* __restrict__ flags) {
  const int bid = blockIdx.x;  // 0..63
  const int tid = threadIdx.x;
  const int w = tid >> 6, lane = tid & 63;
  const int lr = lane & 15;
  const int lk = (lane >> 4) * 8;

  // weight-stationary fragments: w[kk][j] = Whh[bid*16+lr][kk*32+lk+j], hi+lo
  bf16x8_t wfh[32], wfl[32];
  {
    const float* wrow = Whh + (size_t)(bid * 16 + lr) * HIDD + lk;
#pragma unroll
    for (int kk = 0; kk < 32; ++kk) {
      bf16x8_t fh, fl;
#pragma unroll
      for (int j = 0; j < 8; ++j) {
        bf16_t h, l; split_bf16(wrow[kk * 32 + j], h, l);
        fh[j] = h; fl[j] = l;
      }
      wfh[kk] = fh; wfl[kk] = fl;
    }
  }

  const int colg = bid * 16 + lr;
  const int rowb = w * 16 + (lane >> 4) * 4;
  const size_t aoff = (size_t)(w * 16 + lr) * HIDD + lk;

  for (int t = 0; t < SEQ; ++t) {
    // prefetch pre slice early (normal cached loads, streamed once)
    const float* prow = pre + (size_t)t * BH + (size_t)rowb * HIDD + colg;
    float p0 = prow[0], p1 = prow[HIDD], p2 = prow[2 * HIDD], p3 = prow[3 * HIDD];

    float xs0 = 0.f, xs1 = 0.f, xs2 = 0.f, xs3 = 0.f;
    if (t > 0) {
      const bf16_t* arh = Hh + (size_t)(t - 1) * BH + aoff;
      const bf16_t* arl = Hl + (size_t)(t - 1) * BH + aoff;
      f32x4_t a0a = {0.f,0.f,0.f,0.f}, a0b = {0.f,0.f,0.f,0.f};
      f32x4_t a1a = {0.f,0.f,0.f,0.f}, a1b = {0.f,0.f,0.f,0.f};
      f32x4_t a2a = {0.f,0.f,0.f,0.f}, a2b = {0.f,0.f,0.f,0.f};
#pragma unroll
      for (int kk = 0; kk < 32; kk += 2) {
        bf16x8_t h0 = ld_sys_b16x8(arh + kk * 32);
        bf16x8_t l0 = ld_sys_b16x8(arl + kk * 32);
        bf16x8_t h1 = ld_sys_b16x8(arh + (kk + 1) * 32);
        bf16x8_t l1 = ld_sys_b16x8(arl + (kk + 1) * 32);
        a0a = __builtin_amdgcn_mfma_f32_16x16x32_bf16(h0, wfh[kk], a0a, 0, 0, 0);
        a1a = __builtin_amdgcn_mfma_f32_16x16x32_bf16(h0, wfl[kk], a1a, 0, 0, 0);
        a2a = __builtin_amdgcn_mfma_f32_16x16x32_bf16(l0, wfh[kk], a2a, 0, 0, 0);
        a0b = __builtin_amdgcn_mfma_f32_16x16x32_bf16(h1, wfh[kk + 1], a0b, 0, 0, 0);
        a1b = __builtin_amdgcn_mfma_f32_16x16x32_bf16(h1, wfl[kk + 1], a1b, 0, 0, 0);
        a2b = __builtin_amdgcn_mfma_f32_16x16x32_bf16(l1, wfh[kk + 1], a2b, 0, 0, 0);
      }
      xs0 = (a0a[0] + a0b[0]) + (a1a[0] + a1b[0]) + (a2a[0] + a2b[0]);
      xs1 = (a0a[1] + a0b[1]) + (a1a[1] + a1b[1]) + (a2a[1] + a2b[1]);
      xs2 = (a0a[2] + a0b[2]) + (a1a[2] + a1b[2]) + (a2a[2] + a2b[2]);
      xs3 = (a0a[3] + a0b[3]) + (a1a[3] + a1b[3]) + (a2a[3] + a2b[3]);
    }
    bf16_t* nh = Hh + (size_t)t * BH + (size_t)rowb * HIDD + colg;
    bf16_t* nl = Hl + (size_t)t * BH + (size_t)rowb * HIDD + colg;
    float xv[4] = {xs0 + p0, xs1 + p1, xs2 + p2, xs3 + p3};
#pragma unroll
    for (int i = 0; i < 4; ++i) {
      float e = __expf(2.0f * xv[i]);
      float h = 1.0f - 2.0f / (e + 1.0f);
      bf16_t hh, hl; split_bf16(h, hh, hl);
      st_sys_b16(nh + (size_t)i * HIDD, hh);
      st_sys_b16(nl + (size_t)i * HIDD, hl);
    }
    // barrier drains vmcnt(0): all h stores of this block are at the LIC
    __syncthreads();
    if (t < SEQ - 1) {
      if (tid == 0)
        __hip_atomic_store(flags + bid, t + 1, __ATOMIC_RELAXED, __HIP_MEMORY_SCOPE_SYSTEM);
      if (tid < 64) {
        while (__hip_atomic_load(flags + tid, __ATOMIC_RELAXED, __HIP_MEMORY_SCOPE_SYSTEM) < t + 1) { }
      }
      __syncthreads();
    }
  }
}

// ---------------- attention + feat assembly: one block per batch row ---------
// slots 0..510 = prev (h_1..h_511), slot 511 = last (h_512)
__global__ __launch_bounds__(256) void k_attn(const bf16_t* __restrict__ Hh,
                                              const bf16_t* __restrict__ Hl,
                                              bf16_t* __restrict__ feat) {
  __shared__ float sc[512];
  __shared__ float lastf[HIDD];
  __shared__ float red[256];
  const int b = blockIdx.x, tid = threadIdx.x;
  const size_t lastoff = (size_t)511 * BH + (size_t)b * HIDD;
  for (int i = tid; i < HIDD; i += 256)
    lastf[i] = (float)Hh[lastoff + i] + (float)Hl[lastoff + i];
  __syncthreads();
  for (int s = tid; s < 511; s += 256) {
    const size_t hoff = (size_t)s * BH + (size_t)b * HIDD;
    float acc = 0.f;
    for (int k = 0; k < HIDD; k += 8) {
      bf16x8_t vh = *(const bf16x8_t*)(Hh + hoff + k);
      bf16x8_t vl = *(const bf16x8_t*)(Hl + hoff + k);
#pragma unroll
      for (int j = 0; j < 8; ++j)
        acc += ((float)vh[j] + (float)vl[j]) * lastf[k + j];
    }
    sc[s] = acc;
  }
  if (tid == 0) sc[511] = -3.0e38f;
  __syncthreads();
  float m = fmaxf(sc[tid], sc[tid + 256]);
  red[tid] = m; __syncthreads();
  for (int off = 128; off > 0; off >>= 1) {
    if (tid < off) red[tid] = fmaxf(red[tid], red[tid + off]);
    __syncthreads();
  }
  float mall = red[0];
  __syncthreads();
  float e0 = __expf(sc[tid] - mall);
  float e1 = (tid + 256 < 511) ? __expf(sc[tid + 256] - mall) : 0.f;
  red[tid] = e0 + e1; __syncthreads();
  for (int off = 128; off > 0; off >>= 1) {
    if (tid < off) red[tid] += red[tid + off];
    __syncthreads();
  }
  float rsum = 1.0f / red[0];
  __syncthreads();
  sc[tid] = e0 * rsum;
  if (tid + 256 < 511) sc[tid + 256] = e1 * rsum;
  __syncthreads();
  float a0 = 0.f, a1 = 0.f, a2 = 0.f, a3 = 0.f;
  const size_t hb = (size_t)b * HIDD + 4 * tid;
  for (int s = 0; s < 511; ++s) {
    float wgt = sc[s];
    bf16x4_t vh = *(const bf16x4_t*)(Hh + hb + (size_t)s * BH);
    bf16x4_t vl = *(const bf16x4_t*)(Hl + hb + (size_t)s * BH);
    a0 += wgt * ((float)vh[0] + (float)vl[0]);
    a1 += wgt * ((float)vh[1] + (float)vl[1]);
    a2 += wgt * ((float)vh[2] + (float)vl[2]);
    a3 += wgt * ((float)vh[3] + (float)vl[3]);
  }
  bf16x4_t o;
  o[0] = (bf16_t)a0; o[1] = (bf16_t)a1; o[2] = (bf16_t)a2; o[3] = (bf16_t)a3;
  *(bf16x4_t*)(feat + (size_t)b * 2048 + 4 * tid) = o;
  for (int i = tid; i < HIDD; i += 256)
    feat[(size_t)b * 2048 + 1024 + i] = (bf16_t)lastf[i];
}

// ---------------- out = feat @ W_out^T + b_out : M=64,N=32000,K=2048 ---------
__global__ __launch_bounds__(256) void k_out(const bf16_t* __restrict__ feat,
                                             const float* __restrict__ Wout,
                                             const float* __restrict__ bout,
                                             float* __restrict__ out) {
  __shared__ bf16_t As[64 * 64];
  __shared__ bf16_t Bs[128 * 64];
  const int n0 = blockIdx.x * 128;
  const int tid = threadIdx.x;
  const int w = tid >> 6, lane = tid & 63;
  const int lr = lane & 15, lk16 = lane >> 4;
  const int srow = lane >> 3, scol = (lane & 7) * 8;
  f32x4_t acc[4][2];
#pragma unroll
  for (int i = 0; i < 4; ++i)
#pragma unroll
    for (int j = 0; j < 2; ++j) acc[i][j] = (f32x4_t){0.f, 0.f, 0.f, 0.f};

  for (int kt = 0; kt < 32; ++kt) {
    const int k0 = kt * 64;
#pragma unroll
    for (int i = 0; i < 2; ++i) {
      int c = w * 2 + i;  // 0..7, wave-uniform
      const bf16_t* ga = feat + (size_t)(c * 8 + srow) * 2048 + k0 + scol;
      __builtin_amdgcn_global_load_lds((const __attribute__((address_space(1))) void*)ga,
                                       (__attribute__((address_space(3))) void*)(As + c * 512), 16, 0, 0);
    }
    {
      int row = tid >> 1;
      int cbase = (tid & 1) * 32;
      const float* gb = Wout + (size_t)(n0 + row) * 2048 + k0 + cbase;
      bf16_t* db = Bs + row * 64 + cbase;
#pragma unroll
      for (int j = 0; j < 8; ++j) {
        f32x4_t v = *(const f32x4_t*)(gb + j * 4);
        bf16x4_t o;
        o[0] = (bf16_t)v.x; o[1] = (bf16_t)v.y; o[2] = (bf16_t)v.z; o[3] = (bf16_t)v.w;
        *(bf16x4_t*)(db + j * 4) = o;
      }
    }
    __syncthreads();
#pragma unroll
    for (int kk = 0; kk < 2; ++kk) {
      bf16x8_t af[4], bq[2];
#pragma unroll
      for (int mi = 0; mi < 4; ++mi)
        af[mi] = *(const bf16x8_t*)(As + (mi * 16 + lr) * 64 + kk * 32 + lk16 * 8);
#pragma unroll
      for (int ni = 0; ni < 2; ++ni)
        bq[ni] = *(const bf16x8_t*)(Bs + (w * 32 + ni * 16 + lr) * 64 + kk * 32 + lk16 * 8);
#pragma unroll
      for (int mi = 0; mi < 4; ++mi)
#pragma unroll
        for (int ni = 0; ni < 2; ++ni)
          acc[mi][ni] = __builtin_amdgcn_mfma_f32_16x16x32_bf16(af[mi], bq[ni], acc[mi][ni], 0, 0, 0);
    }
    __syncthreads();
  }
#pragma unroll
  for (int ni = 0; ni < 2; ++ni) {
    int col = n0 + w * 32 + ni * 16 + lr;
    float bo = bout[col];
#pragma unroll
    for (int mi = 0; mi < 4; ++mi) {
      int row = mi * 16 + lk16 * 4;
      float* p = out + (size_t)row * NCLASS + col;
#pragma unroll
      for (int i = 0; i < 4; ++i) p[(size_t)i * NCLASS] = acc[mi][ni][i] + bo;
    }
  }
}

extern "C" void kernel_launch(void* const* d_in, const int* in_sizes, int n_in,
                              void* d_out, int out_size, void* d_ws, size_t ws_size,
                              hipStream_t stream) {
  const int*   X    = (const int*)d_in[0];
  const float* emb  = (const float*)d_in[1];
  const float* Wih  = (const float*)d_in[2];
  const float* Whh  = (const float*)d_in[3];
  const float* bih  = (const float*)d_in[4];
  const float* bhh  = (const float*)d_in[5];
  const float* Wout = (const float*)d_in[6];
  const float* bout = (const float*)d_in[7];
  float* out = (float*)d_out;

  char* ws = (char*)d_ws;
  // region A: pre (f32), alive k_pre -> k_rnn
  float*  pre    = (float*)(ws);                      // 134,217,728 B
  // region B (union, temporally disjoint users):
  //   phase1 (k_embg/k_pre): embg hi/lo + Wih hi/lo
  bf16_t* Eh     = (bf16_t*)(ws + 134217728);         // 33,554,432 B
  bf16_t* El     = (bf16_t*)(ws + 167772160);         // 33,554,432 B
  bf16_t* Wihh   = (bf16_t*)(ws + 201326592);         //  1,048,576 B
  bf16_t* Wihl   = (bf16_t*)(ws + 202375168);         //  1,048,576 B
  //   phase2 (k_rnn/k_attn): h state hi/lo, 512 slots each
  bf16_t* Hh     = (bf16_t*)(ws + 134217728);         // 67,108,864 B
  bf16_t* Hl     = (bf16_t*)(ws + 201326592);         // 67,108,864 B
  // region C: small
  bf16_t* feat   = (bf16_t*)(ws + 268435456);         //    262,144 B
  int*    flags  = (int*)(ws + 268697600);            //        256 B

  k_init<<<2048, 256, 0, stream>>>(Wih, Wihh, Wihl, flags);
  k_embg<<<32768, 128, 0, stream>>>(X, emb, Eh, El);
  k_pre<<<dim3(256, 8), 256, 0, stream>>>(Eh, El, Wihh, Wihl, bih, bhh, pre);
  k_rnn<<<64, 256, 0, stream>>>(Whh, pre, Hh, Hl, flags);
  k_attn<<<64, 256, 0, stream>>>(Hh, Hl, feat);
  k_out<<<250, 256, 0, stream>>>(feat, Wout, bout, out);
}